// Round 1
// baseline (73.146 us; speedup 1.0000x reference)
//
#include <hip/hip_runtime.h>

// Neo-Hookean constants (match reference)
#define MU_C   3846.1538461538462f   // E/(2(1+nu))
#define LM_C   5769.2307692307695f   // E*nu/((1+nu)(1-2nu))
#define EPS_C  1e-10f

// B=4, N_QUAD=4, NPE=4 fixed by the reference problem.

__global__ __launch_bounds__(256) void nh_partial(
    const float* __restrict__ u,         // (4, n_nodes, 3)
    const int*   __restrict__ elements,  // (n_elem, 4)
    const float* __restrict__ dN_dx,     // (n_elem, 4, 4, 3)
    const float* __restrict__ detJ,      // (n_elem, 4)
    const float* __restrict__ qw,        // (4,)
    float* __restrict__ partial,         // (gridDim.x, 4)
    int n_elem, int n_nodes)
{
    const int e = blockIdx.x * blockDim.x + threadIdx.x;

    float accb[4] = {0.f, 0.f, 0.f, 0.f};

    if (e < n_elem) {
        // node indices: 16B vector load
        const int4 nd = *reinterpret_cast<const int4*>(elements + (size_t)e * 4);
        const int nodes[4] = {nd.x, nd.y, nd.z, nd.w};

        // dN_dx slab: 48 contiguous floats, 16B-aligned (e*192 bytes)
        float d[48];
        const float4* dp = reinterpret_cast<const float4*>(dN_dx) + (size_t)e * 12;
        #pragma unroll
        for (int k = 0; k < 12; ++k) {
            float4 v = dp[k];
            d[4*k + 0] = v.x; d[4*k + 1] = v.y; d[4*k + 2] = v.z; d[4*k + 3] = v.w;
        }
        // d[(q*4 + n)*3 + j]

        const float4 dj = reinterpret_cast<const float4*>(detJ)[e];
        const float4 w4 = *reinterpret_cast<const float4*>(qw);
        const float wq[4] = {dj.x * w4.x, dj.y * w4.y, dj.z * w4.z, dj.w * w4.w};

        #pragma unroll
        for (int b = 0; b < 4; ++b) {
            // gather u for the 4 nodes of this element, batch b
            float eu[4][3];
            #pragma unroll
            for (int n = 0; n < 4; ++n) {
                const float* up = u + ((size_t)b * n_nodes + nodes[n]) * 3;
                eu[n][0] = up[0]; eu[n][1] = up[1]; eu[n][2] = up[2];
            }

            float a = 0.f;
            #pragma unroll
            for (int q = 0; q < 4; ++q) {
                float F[3][3];
                #pragma unroll
                for (int i = 0; i < 3; ++i) {
                    #pragma unroll
                    for (int j = 0; j < 3; ++j) {
                        float g = 0.f;
                        #pragma unroll
                        for (int n = 0; n < 4; ++n)
                            g = fmaf(eu[n][i], d[(q*4 + n)*3 + j], g);
                        F[i][j] = g + ((i == j) ? 1.f : 0.f);
                    }
                }
                const float J =
                      F[0][0] * (F[1][1]*F[2][2] - F[1][2]*F[2][1])
                    - F[0][1] * (F[1][0]*F[2][2] - F[1][2]*F[2][0])
                    + F[0][2] * (F[1][0]*F[2][1] - F[1][1]*F[2][0]);

                float IC = 0.f;
                #pragma unroll
                for (int i = 0; i < 3; ++i)
                    #pragma unroll
                    for (int j = 0; j < 3; ++j)
                        IC = fmaf(F[i][j], F[i][j], IC);

                const float lj = __logf(fmaxf(J, EPS_C));
                const float W = 0.5f * MU_C * (IC - 3.f - 2.f * lj)
                              + 0.25f * LM_C * (fmaf(J, J, -1.f) - 2.f * lj);
                a = fmaf(W, wq[q], a);
            }
            accb[b] = a;
        }
    }

    // wave(64) shuffle reduction per batch
    #pragma unroll
    for (int b = 0; b < 4; ++b) {
        float v = accb[b];
        #pragma unroll
        for (int off = 32; off > 0; off >>= 1)
            v += __shfl_down(v, off);
        accb[b] = v;   // valid on lane 0 of each wave
    }

    __shared__ float lds[4][4];   // [wave][b]
    const int lane = threadIdx.x & 63;
    const int wid  = threadIdx.x >> 6;
    if (lane == 0) {
        #pragma unroll
        for (int b = 0; b < 4; ++b) lds[wid][b] = accb[b];
    }
    __syncthreads();
    if (threadIdx.x == 0) {
        #pragma unroll
        for (int b = 0; b < 4; ++b)
            partial[(size_t)blockIdx.x * 4 + b] =
                (lds[0][b] + lds[1][b]) + (lds[2][b] + lds[3][b]);
    }
}

__global__ __launch_bounds__(256) void nh_final(
    const float* __restrict__ partial,  // (nparts, 4)
    float* __restrict__ out,            // (4,)
    int nparts)
{
    float accb[4] = {0.f, 0.f, 0.f, 0.f};
    for (int i = threadIdx.x; i < nparts; i += 256) {
        const float4 p = reinterpret_cast<const float4*>(partial)[i];
        accb[0] += p.x; accb[1] += p.y; accb[2] += p.z; accb[3] += p.w;
    }

    #pragma unroll
    for (int b = 0; b < 4; ++b) {
        float v = accb[b];
        #pragma unroll
        for (int off = 32; off > 0; off >>= 1)
            v += __shfl_down(v, off);
        accb[b] = v;
    }

    __shared__ float lds[4][4];
    const int lane = threadIdx.x & 63;
    const int wid  = threadIdx.x >> 6;
    if (lane == 0) {
        #pragma unroll
        for (int b = 0; b < 4; ++b) lds[wid][b] = accb[b];
    }
    __syncthreads();
    if (threadIdx.x == 0) {
        #pragma unroll
        for (int b = 0; b < 4; ++b)
            out[b] = (lds[0][b] + lds[1][b]) + (lds[2][b] + lds[3][b]);
    }
}

extern "C" void kernel_launch(void* const* d_in, const int* in_sizes, int n_in,
                              void* d_out, int out_size, void* d_ws, size_t ws_size,
                              hipStream_t stream) {
    const float* u        = (const float*)d_in[0];
    const int*   elements = (const int*)d_in[1];
    const float* dN_dx    = (const float*)d_in[2];
    const float* detJ     = (const float*)d_in[3];
    const float* qw       = (const float*)d_in[4];
    float* out = (float*)d_out;

    const int B       = out_size;            // 4
    const int n_nodes = in_sizes[0] / (3 * B);
    const int n_elem  = in_sizes[1] / 4;

    const int threads = 256;
    const int nblocks = (n_elem + threads - 1) / threads;

    float* partial = (float*)d_ws;   // nblocks*4 floats, fully overwritten each call

    nh_partial<<<nblocks, threads, 0, stream>>>(u, elements, dN_dx, detJ, qw,
                                                partial, n_elem, n_nodes);
    nh_final<<<1, threads, 0, stream>>>(partial, out, nblocks);
}

// Round 2
// 58.921 us; speedup vs baseline: 1.2414x; 1.2414x over previous
//
#include <hip/hip_runtime.h>

// Neo-Hookean constants (match reference)
#define MU_C   3846.1538461538462f   // E/(2(1+nu))
#define LM_C   5769.2307692307695f   // E*nu/((1+nu)(1-2nu))
#define EPS_C  1e-10f

// B=4, N_QUAD=4, NPE=4 fixed by the reference problem.

// Transpose u (B, n_nodes, 3) -> u_t (n_nodes, B, 3)  [48 B per node, 16B-aligned]
__global__ __launch_bounds__(256) void nh_transpose_u(
    const float* __restrict__ u, float* __restrict__ ut, int n_nodes)
{
    const int i = blockIdx.x * 256 + threadIdx.x;
    if (i >= n_nodes) return;
    float v[4][3];
    #pragma unroll
    for (int b = 0; b < 4; ++b) {
        const float* p = u + ((size_t)b * n_nodes + i) * 3;
        v[b][0] = p[0]; v[b][1] = p[1]; v[b][2] = p[2];
    }
    float4* q4 = reinterpret_cast<float4*>(ut + (size_t)i * 12);
    q4[0] = make_float4(v[0][0], v[0][1], v[0][2], v[1][0]);
    q4[1] = make_float4(v[1][1], v[1][2], v[2][0], v[2][1]);
    q4[2] = make_float4(v[2][2], v[3][0], v[3][1], v[3][2]);
}

// One thread per (element, batch): t = e*4 + b.
// Lanes 4e..4e+3 share all element-indexed loads (merged per instruction).
__global__ __launch_bounds__(256) void nh_partial_eb(
    const float* __restrict__ u,         // (4, n_nodes, 3)   (fallback path)
    const float* __restrict__ ut,        // (n_nodes, 4, 3)   (transposed path)
    const int*   __restrict__ elements,  // (n_elem, 4)
    const float* __restrict__ dN_dx,     // (n_elem, 4, 4, 3)
    const float* __restrict__ detJ,      // (n_elem, 4)
    const float* __restrict__ qw,        // (4,)
    float* __restrict__ partial,         // (gridDim.x, 4)
    int n_elem, int n_nodes, int use_ut)
{
    const int t = blockIdx.x * 256 + threadIdx.x;
    const int e = t >> 2;
    const int b = t & 3;

    float a = 0.f;

    if (e < n_elem) {
        const int4 nd = *reinterpret_cast<const int4*>(elements + (size_t)e * 4);
        const int nodes[4] = {nd.x, nd.y, nd.z, nd.w};

        // element slab: 12 float4, same address for the 4 batch-lanes (merged)
        float4 dv[12];
        const float4* dp = reinterpret_cast<const float4*>(dN_dx) + (size_t)e * 12;
        #pragma unroll
        for (int k = 0; k < 12; ++k) dv[k] = dp[k];
        const float* d = reinterpret_cast<const float*>(dv);  // d[(q*4+n)*3+j], all indices compile-time

        const float4 dj = reinterpret_cast<const float4*>(detJ)[e];
        const float4 w4 = *reinterpret_cast<const float4*>(qw);
        const float wq[4] = {dj.x * w4.x, dj.y * w4.y, dj.z * w4.z, dj.w * w4.w};

        // gather u for this batch only: 4 nodes x 12 B, 32-bit addressing
        float eu[4][3];
        if (use_ut) {
            const float* ub = ut + b * 3;          // + node*12
            #pragma unroll
            for (int n = 0; n < 4; ++n) {
                const float* p = ub + nodes[n] * 12;   // 4 batch-lanes cover one 48B line
                eu[n][0] = p[0]; eu[n][1] = p[1]; eu[n][2] = p[2];
            }
        } else {
            const float* ub = u + (size_t)b * n_nodes * 3;
            #pragma unroll
            for (int n = 0; n < 4; ++n) {
                const float* p = ub + nodes[n] * 3;
                eu[n][0] = p[0]; eu[n][1] = p[1]; eu[n][2] = p[2];
            }
        }

        #pragma unroll
        for (int q = 0; q < 4; ++q) {
            float F[3][3];
            #pragma unroll
            for (int i = 0; i < 3; ++i) {
                #pragma unroll
                for (int j = 0; j < 3; ++j) {
                    float g = 0.f;
                    #pragma unroll
                    for (int n = 0; n < 4; ++n)
                        g = fmaf(eu[n][i], d[(q*4 + n)*3 + j], g);
                    F[i][j] = g + ((i == j) ? 1.f : 0.f);
                }
            }
            const float J =
                  F[0][0] * (F[1][1]*F[2][2] - F[1][2]*F[2][1])
                - F[0][1] * (F[1][0]*F[2][2] - F[1][2]*F[2][0])
                + F[0][2] * (F[1][0]*F[2][1] - F[1][1]*F[2][0]);

            float IC = 0.f;
            #pragma unroll
            for (int i = 0; i < 3; ++i)
                #pragma unroll
                for (int j = 0; j < 3; ++j)
                    IC = fmaf(F[i][j], F[i][j], IC);

            const float lj = __logf(fmaxf(J, EPS_C));
            const float W = 0.5f * MU_C * (IC - 3.f - 2.f * lj)
                          + 0.25f * LM_C * (fmaf(J, J, -1.f) - 2.f * lj);
            a = fmaf(W, wq[q], a);
        }
    }

    // reduce across lanes with the same b (stride-4 groups): offsets 32,16,8,4
    #pragma unroll
    for (int off = 32; off >= 4; off >>= 1)
        a += __shfl_down(a, off);
    // lanes 0..3 now hold this wave's batch sums

    __shared__ float lds[4][4];   // [wave][b]
    const int lane = threadIdx.x & 63;
    const int wid  = threadIdx.x >> 6;
    if (lane < 4) lds[wid][lane] = a;
    __syncthreads();
    if (threadIdx.x < 4)
        partial[(size_t)blockIdx.x * 4 + threadIdx.x] =
            (lds[0][threadIdx.x] + lds[1][threadIdx.x]) +
            (lds[2][threadIdx.x] + lds[3][threadIdx.x]);
}

__global__ __launch_bounds__(256) void nh_final(
    const float* __restrict__ partial,  // (nparts, 4)
    float* __restrict__ out,            // (4,)
    int nparts)
{
    float accb[4] = {0.f, 0.f, 0.f, 0.f};
    for (int i = threadIdx.x; i < nparts; i += 256) {
        const float4 p = reinterpret_cast<const float4*>(partial)[i];
        accb[0] += p.x; accb[1] += p.y; accb[2] += p.z; accb[3] += p.w;
    }

    #pragma unroll
    for (int b = 0; b < 4; ++b) {
        float v = accb[b];
        #pragma unroll
        for (int off = 32; off > 0; off >>= 1)
            v += __shfl_down(v, off);
        accb[b] = v;
    }

    __shared__ float lds[4][4];
    const int lane = threadIdx.x & 63;
    const int wid  = threadIdx.x >> 6;
    if (lane == 0) {
        #pragma unroll
        for (int b = 0; b < 4; ++b) lds[wid][b] = accb[b];
    }
    __syncthreads();
    if (threadIdx.x == 0) {
        #pragma unroll
        for (int b = 0; b < 4; ++b)
            out[b] = (lds[0][b] + lds[1][b]) + (lds[2][b] + lds[3][b]);
    }
}

extern "C" void kernel_launch(void* const* d_in, const int* in_sizes, int n_in,
                              void* d_out, int out_size, void* d_ws, size_t ws_size,
                              hipStream_t stream) {
    const float* u        = (const float*)d_in[0];
    const int*   elements = (const int*)d_in[1];
    const float* dN_dx    = (const float*)d_in[2];
    const float* detJ     = (const float*)d_in[3];
    const float* qw       = (const float*)d_in[4];
    float* out = (float*)d_out;

    const int B       = out_size;            // 4
    const int n_nodes = in_sizes[0] / (3 * B);
    const int n_elem  = in_sizes[1] / 4;

    const int threads = 256;
    const int n_thr   = n_elem * 4;                       // (element, batch)
    const int nblocks = (n_thr + threads - 1) / threads;

    const size_t ut_bytes      = (size_t)n_nodes * 48;    // (n_nodes, 4, 3) fp32
    const size_t partial_bytes = (size_t)nblocks * 4 * sizeof(float);
    const int use_ut = (ws_size >= ut_bytes + partial_bytes) ? 1 : 0;

    float* ut      = (float*)d_ws;
    float* partial = use_ut ? (float*)((char*)d_ws + ut_bytes) : (float*)d_ws;

    if (use_ut) {
        const int tb = (n_nodes + threads - 1) / threads;
        nh_transpose_u<<<tb, threads, 0, stream>>>(u, ut, n_nodes);
    }

    nh_partial_eb<<<nblocks, threads, 0, stream>>>(u, ut, elements, dN_dx, detJ, qw,
                                                   partial, n_elem, n_nodes, use_ut);
    nh_final<<<1, threads, 0, stream>>>(partial, out, nblocks);
}